// Round 1
// baseline (2301.625 us; speedup 1.0000x reference)
//
#include <hip/hip_runtime.h>

// Problem constants (fixed by the reference).
#define N_NODES   50000
#define N_EDGES   400000
#define IN_DIM    128
#define OUT_DIM   32
#define EDGE_DIM  64
#define HEADS     8
#define HC        256          // HEADS * OUT_DIM
#define N_REL     512
#define NEG_SLOPE 0.2f
#define E_TOT     (N_EDGES + N_NODES)   // edges + self loops

// ---------------------------------------------------------------------------
// rel_emb[r, :] = relations[r, :] @ W_e          (512 x 64) @ (64 x 256)
// ---------------------------------------------------------------------------
__global__ void k_rel_emb(const float* __restrict__ relations,
                          const float* __restrict__ W_e,
                          float* __restrict__ rel_emb) {
    __shared__ float row[EDGE_DIM];
    const int r = blockIdx.x;
    const int j = threadIdx.x;           // 0..255
    if (j < EDGE_DIM) row[j] = relations[r * EDGE_DIM + j];
    __syncthreads();
    float acc = 0.f;
#pragma unroll
    for (int k = 0; k < EDGE_DIM; ++k)
        acc = fmaf(row[k], W_e[k * HC + j], acc);
    rel_emb[r * HC + j] = acc;
}

// ---------------------------------------------------------------------------
// Scatter pass: deg[dst] += 1, attr_sum[dst, c] += relations[rel, c]
// One wave (64 lanes) per edge; lane = channel (EDGE_DIM == 64).
// ---------------------------------------------------------------------------
__global__ void __launch_bounds__(256) k_scatter(
        const int* __restrict__ dst_arr,
        const int* __restrict__ rel_idx,
        const float* __restrict__ relations,
        float* __restrict__ attr_sum,
        float* __restrict__ deg) {
    const int e = (blockIdx.x * 256 + threadIdx.x) >> 6;
    if (e >= N_EDGES) return;
    const int lane = threadIdx.x & 63;
    const int d = dst_arr[e];
    const int r = rel_idx[e];
    atomicAdd(&attr_sum[d * EDGE_DIM + lane], relations[r * EDGE_DIM + lane]);
    if (lane == 0) atomicAdd(&deg[d], 1.0f);
}

// ---------------------------------------------------------------------------
// Node projections: x_l = x@W_l + b_l, x_r = x@W_r + b_r,
//                   self_emb = (attr_sum / max(deg,1)) @ W_e
// One block (256 threads) per node; thread j owns output column j.
// ---------------------------------------------------------------------------
__global__ void __launch_bounds__(256) k_node(
        const float* __restrict__ x,
        const float* __restrict__ W_l, const float* __restrict__ b_l,
        const float* __restrict__ W_r, const float* __restrict__ b_r,
        const float* __restrict__ W_e,
        const float* __restrict__ attr_sum, const float* __restrict__ deg,
        float* __restrict__ x_l, float* __restrict__ x_r,
        float* __restrict__ self_emb) {
    __shared__ float xs[IN_DIM];
    __shared__ float as[EDGE_DIM];
    const int n = blockIdx.x;
    const int j = threadIdx.x;           // 0..255
    if (j < IN_DIM) xs[j] = x[n * IN_DIM + j];
    if (j >= IN_DIM && j < IN_DIM + EDGE_DIM) {
        const float dg = fmaxf(deg[n], 1.0f);
        as[j - IN_DIM] = attr_sum[n * EDGE_DIM + (j - IN_DIM)] / dg;
    }
    __syncthreads();
    float al = b_l[j];
    float ar = b_r[j];
#pragma unroll 8
    for (int k = 0; k < IN_DIM; ++k) {
        const float xv = xs[k];
        al = fmaf(xv, W_l[k * HC + j], al);
        ar = fmaf(xv, W_r[k * HC + j], ar);
    }
    float ae = 0.f;
#pragma unroll 8
    for (int k = 0; k < EDGE_DIM; ++k)
        ae = fmaf(as[k], W_e[k * HC + j], ae);
    x_l[n * HC + j] = al;
    x_r[n * HC + j] = ar;
    self_emb[n * HC + j] = ae;
}

// ---------------------------------------------------------------------------
// Edge pass (E + N self-loops). One wave per edge.
// lane -> (h = lane>>3, q = lane&7); each lane handles a float4 chunk.
//   logit[h] = sum_c att[h,c] * lrelu(x_l[s,h,c] + x_r[d,h,c] + e_emb[h,c])
//   ex = exp(logit)           (no max subtraction; logits are O(7) — safe f32)
//   denom[d,h]      += ex
//   out_acc[d,h,c]  += ex * x_l[s,h,c]
// ---------------------------------------------------------------------------
__global__ void __launch_bounds__(256) k_edge(
        const int* __restrict__ src_arr, const int* __restrict__ dst_arr,
        const int* __restrict__ rel_idx,
        const float* __restrict__ x_l, const float* __restrict__ x_r,
        const float* __restrict__ rel_emb, const float* __restrict__ self_emb,
        const float* __restrict__ att,
        float* __restrict__ denom, float* __restrict__ out_acc) {
    const int e = (blockIdx.x * 256 + threadIdx.x) >> 6;
    if (e >= E_TOT) return;
    const int lane = threadIdx.x & 63;
    const int h = lane >> 3;
    const int q = lane & 7;
    const int off = h * OUT_DIM + q * 4;

    int s, d;
    const float* ee;
    if (e < N_EDGES) {
        s = src_arr[e];
        d = dst_arr[e];
        ee = rel_emb + rel_idx[e] * HC;
    } else {
        s = d = e - N_EDGES;
        ee = self_emb + s * HC;
    }

    const float4 xl = *(const float4*)(x_l + s * HC + off);
    const float4 xr = *(const float4*)(x_r + d * HC + off);
    const float4 ev = *(const float4*)(ee + off);
    const float4 at = *(const float4*)(att + off);

    float m0 = xl.x + xr.x + ev.x; m0 = m0 >= 0.f ? m0 : NEG_SLOPE * m0;
    float m1 = xl.y + xr.y + ev.y; m1 = m1 >= 0.f ? m1 : NEG_SLOPE * m1;
    float m2 = xl.z + xr.z + ev.z; m2 = m2 >= 0.f ? m2 : NEG_SLOPE * m2;
    float m3 = xl.w + xr.w + ev.w; m3 = m3 >= 0.f ? m3 : NEG_SLOPE * m3;

    float p = at.x * m0 + at.y * m1 + at.z * m2 + at.w * m3;
    // reduce across the 8 lanes of this head (xor masks stay inside group)
    p += __shfl_xor(p, 1);
    p += __shfl_xor(p, 2);
    p += __shfl_xor(p, 4);

    const float ex = expf(p);
    if (q == 0) atomicAdd(&denom[d * HEADS + h], ex);

    float* oa = out_acc + d * HC + off;
    atomicAdd(oa + 0, ex * xl.x);
    atomicAdd(oa + 1, ex * xl.y);
    atomicAdd(oa + 2, ex * xl.z);
    atomicAdd(oa + 3, ex * xl.w);
}

// ---------------------------------------------------------------------------
// Epilogue: out[n,c] = mean_h( out_acc[n,h,c] / denom[n,h] ) + bias[c]
// ---------------------------------------------------------------------------
__global__ void __launch_bounds__(256) k_final(
        const float* __restrict__ out_acc,
        const float* __restrict__ denom,
        const float* __restrict__ bias,
        float* __restrict__ out) {
    const int gid = blockIdx.x * 256 + threadIdx.x;
    if (gid >= N_NODES * OUT_DIM) return;
    const int n = gid >> 5;
    const int c = gid & 31;
    float acc = 0.f;
#pragma unroll
    for (int h = 0; h < HEADS; ++h)
        acc += out_acc[n * HC + h * OUT_DIM + c] / denom[n * HEADS + h];
    out[gid] = acc * (1.0f / HEADS) + bias[c];
}

__global__ void k_copy_rel(const float* __restrict__ relations,
                           float* __restrict__ out_tail) {
    const int i = blockIdx.x * 256 + threadIdx.x;
    if (i < N_REL * EDGE_DIM) out_tail[i] = relations[i];
}

// ---------------------------------------------------------------------------
extern "C" void kernel_launch(void* const* d_in, const int* in_sizes, int n_in,
                              void* d_out, int out_size, void* d_ws, size_t ws_size,
                              hipStream_t stream) {
    const float* x         = (const float*)d_in[0];
    const int*   edge_idx  = (const int*)d_in[1];
    const float* relations = (const float*)d_in[2];
    const int*   rel_idx   = (const int*)d_in[3];
    const float* W_l       = (const float*)d_in[4];
    const float* b_l       = (const float*)d_in[5];
    const float* W_r       = (const float*)d_in[6];
    const float* b_r       = (const float*)d_in[7];
    const float* W_e       = (const float*)d_in[8];
    const float* att       = (const float*)d_in[9];
    const float* bias      = (const float*)d_in[10];

    const int* src_arr = edge_idx;            // edge_index[0, :]
    const int* dst_arr = edge_idx + N_EDGES;  // edge_index[1, :]

    float* out      = (float*)d_out;                 // [N, 32]
    float* out_tail = out + N_NODES * OUT_DIM;       // relations copy

    // Workspace layout (floats)
    float* ws       = (float*)d_ws;
    float* x_l      = ws;                                  // 12.8M
    float* x_r      = x_l + (size_t)N_NODES * HC;          // 12.8M
    float* self_emb = x_r + (size_t)N_NODES * HC;          // 12.8M
    float* rel_emb  = self_emb + (size_t)N_NODES * HC;     // 131072
    // --- zeroed region starts here (contiguous, one memset) ---
    float* attr_sum = rel_emb + (size_t)N_REL * HC;        // 3.2M
    float* deg      = attr_sum + (size_t)N_NODES * EDGE_DIM; // 50K
    float* denom    = deg + N_NODES;                       // 400K
    float* out_acc  = denom + (size_t)N_NODES * HEADS;     // 12.8M
    const size_t zero_bytes =
        ((size_t)N_NODES * EDGE_DIM + N_NODES +
         (size_t)N_NODES * HEADS + (size_t)N_NODES * HC) * sizeof(float);

    hipMemsetAsync(attr_sum, 0, zero_bytes, stream);

    k_rel_emb<<<N_REL, 256, 0, stream>>>(relations, W_e, rel_emb);

    k_scatter<<<(N_EDGES + 3) / 4, 256, 0, stream>>>(
        dst_arr, rel_idx, relations, attr_sum, deg);

    k_node<<<N_NODES, 256, 0, stream>>>(
        x, W_l, b_l, W_r, b_r, W_e, attr_sum, deg, x_l, x_r, self_emb);

    k_edge<<<(E_TOT + 3) / 4, 256, 0, stream>>>(
        src_arr, dst_arr, rel_idx, x_l, x_r, rel_emb, self_emb, att,
        denom, out_acc);

    k_final<<<(N_NODES * OUT_DIM + 255) / 256, 256, 0, stream>>>(
        out_acc, denom, bias, out);

    k_copy_rel<<<(N_REL * EDGE_DIM + 255) / 256, 256, 0, stream>>>(
        relations, out_tail);
}

// Round 2
// 389.298 us; speedup vs baseline: 5.9122x; 5.9122x over previous
//
#include <hip/hip_runtime.h>

// Problem constants (fixed by the reference).
#define N_NODES   50000
#define N_EDGES   400000
#define IN_DIM    128
#define OUT_DIM   32
#define EDGE_DIM  64
#define HEADS     8
#define HC        256          // HEADS * OUT_DIM
#define N_REL     512
#define NEG_SLOPE 0.2f
#define NB_SCAN   196          // ceil(50000/256)

// ---------------------------------------------------------------------------
// rel_emb[r, :] = relations[r, :] @ W_e          (512 x 64) @ (64 x 256)
// ---------------------------------------------------------------------------
__global__ void k_rel_emb(const float* __restrict__ relations,
                          const float* __restrict__ W_e,
                          float* __restrict__ rel_emb) {
    __shared__ float row[EDGE_DIM];
    const int r = blockIdx.x;
    const int j = threadIdx.x;           // 0..255
    if (j < EDGE_DIM) row[j] = relations[r * EDGE_DIM + j];
    __syncthreads();
    float acc = 0.f;
#pragma unroll
    for (int k = 0; k < EDGE_DIM; ++k)
        acc = fmaf(row[k], W_e[k * HC + j], acc);
    rel_emb[r * HC + j] = acc;
}

// ---------------------------------------------------------------------------
// Degree histogram (int).
// ---------------------------------------------------------------------------
__global__ void k_deg(const int* __restrict__ dst_arr, int* __restrict__ deg_i) {
    const int e = blockIdx.x * 256 + threadIdx.x;
    if (e < N_EDGES) atomicAdd(&deg_i[dst_arr[e]], 1);
}

// ---------------------------------------------------------------------------
// Block-level inclusive scan of deg -> incl, block sums -> partials.
// ---------------------------------------------------------------------------
__global__ void __launch_bounds__(256) k_scan_a(const int* __restrict__ deg_i,
                                                int* __restrict__ incl,
                                                int* __restrict__ partials) {
    __shared__ int s[256];
    const int i = blockIdx.x * 256 + threadIdx.x;
    const int v = (i < N_NODES) ? deg_i[i] : 0;
    s[threadIdx.x] = v;
    __syncthreads();
#pragma unroll
    for (int o = 1; o < 256; o <<= 1) {
        int t = s[threadIdx.x];
        if (threadIdx.x >= o) t += s[threadIdx.x - o];
        __syncthreads();
        s[threadIdx.x] = t;
        __syncthreads();
    }
    if (i < N_NODES) incl[i] = s[threadIdx.x];
    if (threadIdx.x == 255) partials[blockIdx.x] = s[255];
}

// Exclusive scan of the NB_SCAN block sums (in place).
__global__ void __launch_bounds__(256) k_scan_b(int* __restrict__ partials) {
    __shared__ int s[256];
    const int v = (threadIdx.x < NB_SCAN) ? partials[threadIdx.x] : 0;
    s[threadIdx.x] = v;
    __syncthreads();
#pragma unroll
    for (int o = 1; o < 256; o <<= 1) {
        int t = s[threadIdx.x];
        if (threadIdx.x >= o) t += s[threadIdx.x - o];
        __syncthreads();
        s[threadIdx.x] = t;
        __syncthreads();
    }
    if (threadIdx.x < NB_SCAN) partials[threadIdx.x] = s[threadIdx.x] - v;
}

// row_ptr[i] = exclusive global scan; row_ptr[N] = E.
__global__ void __launch_bounds__(256) k_scan_c(const int* __restrict__ incl,
                                                const int* __restrict__ deg_i,
                                                const int* __restrict__ partials,
                                                int* __restrict__ row_ptr) {
    const int i = blockIdx.x * 256 + threadIdx.x;
    if (i < N_NODES) row_ptr[i] = incl[i] - deg_i[i] + partials[blockIdx.x];
    if (i == 0) row_ptr[N_NODES] = N_EDGES;
}

// ---------------------------------------------------------------------------
// Scatter (src, rel) into CSR slots.
// ---------------------------------------------------------------------------
__global__ void k_fill(const int* __restrict__ src_arr,
                       const int* __restrict__ dst_arr,
                       const int* __restrict__ rel_idx,
                       const int* __restrict__ row_ptr,
                       int* __restrict__ cursor,
                       int2* __restrict__ csr) {
    const int e = blockIdx.x * 256 + threadIdx.x;
    if (e >= N_EDGES) return;
    const int d = dst_arr[e];
    const int pos = row_ptr[d] + atomicAdd(&cursor[d], 1);
    csr[pos] = make_int2(src_arr[e], rel_idx[e]);
}

// ---------------------------------------------------------------------------
// self_attr[n, :] = mean of relations[rel] over incoming edges (CSR walk).
// One wave per node; lane = channel.
// ---------------------------------------------------------------------------
__global__ void __launch_bounds__(256) k_selfattr(
        const int* __restrict__ row_ptr, const int2* __restrict__ csr,
        const float* __restrict__ relations, float* __restrict__ self_attr) {
    const int n = (blockIdx.x * 256 + threadIdx.x) >> 6;
    if (n >= N_NODES) return;
    const int lane = threadIdx.x & 63;
    const int beg = row_ptr[n], end = row_ptr[n + 1];
    float a = 0.f;
    for (int i = beg; i < end; ++i) {
        const int r = csr[i].y;
        a += relations[r * EDGE_DIM + lane];
    }
    const float dg = (float)max(end - beg, 1);
    self_attr[n * EDGE_DIM + lane] = a / dg;
}

// ---------------------------------------------------------------------------
// Node projections, 8 nodes per block to amortize weight reads.
//   x_l = x@W_l + b_l, x_r = x@W_r + b_r, self_emb = self_attr @ W_e
// Thread j owns output column j for all 8 nodes.
// ---------------------------------------------------------------------------
__global__ void __launch_bounds__(256) k_node(
        const float* __restrict__ x,
        const float* __restrict__ W_l, const float* __restrict__ b_l,
        const float* __restrict__ W_r, const float* __restrict__ b_r,
        const float* __restrict__ W_e,
        const float* __restrict__ self_attr,
        float* __restrict__ x_l, float* __restrict__ x_r,
        float* __restrict__ self_emb) {
    __shared__ float xs[8][IN_DIM];
    __shared__ float as[8][EDGE_DIM];
    const int n0 = blockIdx.x * 8;
    const int j = threadIdx.x;
    for (int t = j; t < 8 * IN_DIM; t += 256) {
        const int ni = t >> 7, k = t & 127;
        xs[ni][k] = x[(size_t)(n0 + ni) * IN_DIM + k];
    }
    for (int t = j; t < 8 * EDGE_DIM; t += 256) {
        const int ni = t >> 6, k = t & 63;
        as[ni][k] = self_attr[(size_t)(n0 + ni) * EDGE_DIM + k];
    }
    __syncthreads();
    const float bl = b_l[j], br = b_r[j];
    float al[8], ar[8], ae[8];
#pragma unroll
    for (int ni = 0; ni < 8; ++ni) { al[ni] = bl; ar[ni] = br; ae[ni] = 0.f; }

    for (int k = 0; k < IN_DIM; k += 4) {
        const float wl0 = W_l[(k + 0) * HC + j], wl1 = W_l[(k + 1) * HC + j];
        const float wl2 = W_l[(k + 2) * HC + j], wl3 = W_l[(k + 3) * HC + j];
        const float wr0 = W_r[(k + 0) * HC + j], wr1 = W_r[(k + 1) * HC + j];
        const float wr2 = W_r[(k + 2) * HC + j], wr3 = W_r[(k + 3) * HC + j];
#pragma unroll
        for (int ni = 0; ni < 8; ++ni) {
            const float4 xv = *(const float4*)&xs[ni][k];
            al[ni] = fmaf(xv.x, wl0, fmaf(xv.y, wl1, fmaf(xv.z, wl2, fmaf(xv.w, wl3, al[ni]))));
            ar[ni] = fmaf(xv.x, wr0, fmaf(xv.y, wr1, fmaf(xv.z, wr2, fmaf(xv.w, wr3, ar[ni]))));
        }
    }
    for (int k = 0; k < EDGE_DIM; k += 4) {
        const float we0 = W_e[(k + 0) * HC + j], we1 = W_e[(k + 1) * HC + j];
        const float we2 = W_e[(k + 2) * HC + j], we3 = W_e[(k + 3) * HC + j];
#pragma unroll
        for (int ni = 0; ni < 8; ++ni) {
            const float4 av = *(const float4*)&as[ni][k];
            ae[ni] = fmaf(av.x, we0, fmaf(av.y, we1, fmaf(av.z, we2, fmaf(av.w, we3, ae[ni]))));
        }
    }
#pragma unroll
    for (int ni = 0; ni < 8; ++ni) {
        x_l[(size_t)(n0 + ni) * HC + j] = al[ni];
        x_r[(size_t)(n0 + ni) * HC + j] = ar[ni];
        self_emb[(size_t)(n0 + ni) * HC + j] = ae[ni];
    }
}

// ---------------------------------------------------------------------------
// Aggregation: one wave per destination node. Register accumulation, no
// atomics. lane -> (h = lane>>3, q = lane&7), float4 chunk per lane.
// Fuses softmax normalization, head mean, and bias (old k_final).
// ---------------------------------------------------------------------------
__global__ void __launch_bounds__(256) k_agg(
        const int* __restrict__ row_ptr, const int2* __restrict__ csr,
        const float* __restrict__ x_l, const float* __restrict__ x_r,
        const float* __restrict__ rel_emb, const float* __restrict__ self_emb,
        const float* __restrict__ att, const float* __restrict__ bias,
        float* __restrict__ out) {
    const int n = (blockIdx.x * 256 + threadIdx.x) >> 6;
    if (n >= N_NODES) return;
    const int lane = threadIdx.x & 63;
    const int q = lane & 7;
    const int off = (lane >> 3) * OUT_DIM + q * 4;

    const float4 at = *(const float4*)(att + off);
    const float4 xr = *(const float4*)(x_r + (size_t)n * HC + off);

    // Self-loop term.
    const float4 xls = *(const float4*)(x_l + (size_t)n * HC + off);
    const float4 se  = *(const float4*)(self_emb + (size_t)n * HC + off);
    float m0 = xls.x + xr.x + se.x; m0 = m0 >= 0.f ? m0 : NEG_SLOPE * m0;
    float m1 = xls.y + xr.y + se.y; m1 = m1 >= 0.f ? m1 : NEG_SLOPE * m1;
    float m2 = xls.z + xr.z + se.z; m2 = m2 >= 0.f ? m2 : NEG_SLOPE * m2;
    float m3 = xls.w + xr.w + se.w; m3 = m3 >= 0.f ? m3 : NEG_SLOPE * m3;
    float p = at.x * m0 + at.y * m1 + at.z * m2 + at.w * m3;
    p += __shfl_xor(p, 1);
    p += __shfl_xor(p, 2);
    p += __shfl_xor(p, 4);
    float ex = __expf(p);
    float den = ex;
    float4 acc;
    acc.x = ex * xls.x; acc.y = ex * xls.y; acc.z = ex * xls.z; acc.w = ex * xls.w;

    const int beg = row_ptr[n], end = row_ptr[n + 1];
    for (int i = beg; i < end; ++i) {
        const int2 sr = csr[i];
        const float4 xl = *(const float4*)(x_l + (size_t)sr.x * HC + off);
        const float4 ev = *(const float4*)(rel_emb + (size_t)sr.y * HC + off);
        float a0 = xl.x + xr.x + ev.x; a0 = a0 >= 0.f ? a0 : NEG_SLOPE * a0;
        float a1 = xl.y + xr.y + ev.y; a1 = a1 >= 0.f ? a1 : NEG_SLOPE * a1;
        float a2 = xl.z + xr.z + ev.z; a2 = a2 >= 0.f ? a2 : NEG_SLOPE * a2;
        float a3 = xl.w + xr.w + ev.w; a3 = a3 >= 0.f ? a3 : NEG_SLOPE * a3;
        float pp = at.x * a0 + at.y * a1 + at.z * a2 + at.w * a3;
        pp += __shfl_xor(pp, 1);
        pp += __shfl_xor(pp, 2);
        pp += __shfl_xor(pp, 4);
        const float e2 = __expf(pp);
        den += e2;
        acc.x = fmaf(e2, xl.x, acc.x);
        acc.y = fmaf(e2, xl.y, acc.y);
        acc.z = fmaf(e2, xl.z, acc.z);
        acc.w = fmaf(e2, xl.w, acc.w);
    }

    // Normalize per head, then mean over heads (reduce across lane bits 3..5).
    const float inv = 1.f / den;
    float4 v;
    v.x = acc.x * inv; v.y = acc.y * inv; v.z = acc.z * inv; v.w = acc.w * inv;
    v.x += __shfl_xor(v.x, 8);  v.y += __shfl_xor(v.y, 8);
    v.z += __shfl_xor(v.z, 8);  v.w += __shfl_xor(v.w, 8);
    v.x += __shfl_xor(v.x, 16); v.y += __shfl_xor(v.y, 16);
    v.z += __shfl_xor(v.z, 16); v.w += __shfl_xor(v.w, 16);
    v.x += __shfl_xor(v.x, 32); v.y += __shfl_xor(v.y, 32);
    v.z += __shfl_xor(v.z, 32); v.w += __shfl_xor(v.w, 32);
    if (lane < 8) {
        const float4 bs = *(const float4*)(bias + q * 4);
        float4 o;
        o.x = v.x * 0.125f + bs.x;
        o.y = v.y * 0.125f + bs.y;
        o.z = v.z * 0.125f + bs.z;
        o.w = v.w * 0.125f + bs.w;
        *(float4*)(out + (size_t)n * OUT_DIM + q * 4) = o;
    }
}

__global__ void k_copy_rel(const float* __restrict__ relations,
                           float* __restrict__ out_tail) {
    const int i = blockIdx.x * 256 + threadIdx.x;
    if (i < N_REL * EDGE_DIM) out_tail[i] = relations[i];
}

// ---------------------------------------------------------------------------
extern "C" void kernel_launch(void* const* d_in, const int* in_sizes, int n_in,
                              void* d_out, int out_size, void* d_ws, size_t ws_size,
                              hipStream_t stream) {
    const float* x         = (const float*)d_in[0];
    const int*   edge_idx  = (const int*)d_in[1];
    const float* relations = (const float*)d_in[2];
    const int*   rel_idx   = (const int*)d_in[3];
    const float* W_l       = (const float*)d_in[4];
    const float* b_l       = (const float*)d_in[5];
    const float* W_r       = (const float*)d_in[6];
    const float* b_r       = (const float*)d_in[7];
    const float* W_e       = (const float*)d_in[8];
    const float* att       = (const float*)d_in[9];
    const float* bias      = (const float*)d_in[10];

    const int* src_arr = edge_idx;            // edge_index[0, :]
    const int* dst_arr = edge_idx + N_EDGES;  // edge_index[1, :]

    float* out      = (float*)d_out;                 // [N, 32]
    float* out_tail = out + N_NODES * OUT_DIM;       // relations copy

    // Workspace layout (16B-aligned chunks; all counts multiple of 4).
    float* ws        = (float*)d_ws;
    float* x_l       = ws;                                    // 12.8M f
    float* x_r       = x_l + (size_t)N_NODES * HC;            // 12.8M f
    float* self_emb  = x_r + (size_t)N_NODES * HC;            // 12.8M f
    float* rel_emb   = self_emb + (size_t)N_NODES * HC;       // 131072 f
    float* self_attr = rel_emb + (size_t)N_REL * HC;          // 3.2M f
    int*   ibase     = (int*)(self_attr + (size_t)N_NODES * EDGE_DIM);
    int2*  csr       = (int2*)ibase;                          // 400000 int2
    int*   row_ptr   = ibase + 2 * N_EDGES;                   // 50001 (+pad 3)
    int*   incl      = row_ptr + N_NODES + 4;                 // 50000
    int*   deg_i     = incl + N_NODES;                        // 50000 \ zeroed
    int*   cursor    = deg_i + N_NODES;                       // 50000 / together
    int*   partials  = cursor + N_NODES;                      // 256

    hipMemsetAsync(deg_i, 0, 2 * N_NODES * sizeof(int), stream);

    k_rel_emb<<<N_REL, 256, 0, stream>>>(relations, W_e, rel_emb);

    k_deg<<<(N_EDGES + 255) / 256, 256, 0, stream>>>(dst_arr, deg_i);
    k_scan_a<<<NB_SCAN, 256, 0, stream>>>(deg_i, incl, partials);
    k_scan_b<<<1, 256, 0, stream>>>(partials);
    k_scan_c<<<NB_SCAN, 256, 0, stream>>>(incl, deg_i, partials, row_ptr);
    k_fill<<<(N_EDGES + 255) / 256, 256, 0, stream>>>(
        src_arr, dst_arr, rel_idx, row_ptr, cursor, csr);

    k_selfattr<<<(N_NODES * 64 + 255) / 256, 256, 0, stream>>>(
        row_ptr, csr, relations, self_attr);

    k_node<<<N_NODES / 8, 256, 0, stream>>>(
        x, W_l, b_l, W_r, b_r, W_e, self_attr, x_l, x_r, self_emb);

    k_agg<<<(N_NODES * 64 + 255) / 256, 256, 0, stream>>>(
        row_ptr, csr, x_l, x_r, rel_emb, self_emb, att, bias, out);

    k_final_unused:;
    k_copy_rel<<<(N_REL * EDGE_DIM + 255) / 256, 256, 0, stream>>>(
        relations, out_tail);
}